// Round 10
// baseline (150.303 us; speedup 1.0000x reference)
//
#include <hip/hip_runtime.h>
#include <hip/hip_bf16.h>

typedef __attribute__((ext_vector_type(8))) short bf16x8;
typedef __attribute__((ext_vector_type(4))) short s16x4;
typedef __attribute__((ext_vector_type(4))) float f32x4;

__device__ __forceinline__ short f2bf(float f) {
    unsigned int u = __builtin_bit_cast(unsigned int, f);
    u += 0x7fffu + ((u >> 16) & 1u);
    return (short)(u >> 16);
}

#define GLDS(g, l) __builtin_amdgcn_global_load_lds( \
    (__attribute__((address_space(1))) void*)(g),    \
    (__attribute__((address_space(3))) void*)(l), 16, 0, 0)

#define BARSB() { __builtin_amdgcn_s_barrier(); __builtin_amdgcn_sched_barrier(0); }
#define LGKM0() { asm volatile("s_waitcnt lgkmcnt(0)" ::: "memory"); __builtin_amdgcn_sched_barrier(0); }
#define VMC8()  { asm volatile("s_waitcnt vmcnt(8)" ::: "memory"); __builtin_amdgcn_sched_barrier(0); }
#define VMC2()  { asm volatile("s_waitcnt vmcnt(2)" ::: "memory"); __builtin_amdgcn_sched_barrier(0); }
#define VMC0()  { asm volatile("s_waitcnt vmcnt(0)" ::: "memory"); __builtin_amdgcn_sched_barrier(0); }

// ---------------- fp32 -> bf16 convert ----------------
__global__ __launch_bounds__(256) void cvt_kernel(const float* __restrict__ in,
                                                  short* __restrict__ out, int n4) {
    int i = blockIdx.x * 256 + threadIdx.x;
    if (i >= n4) return;
    float4 v = reinterpret_cast<const float4*>(in)[i];
    s16x4 r = { f2bf(v.x), f2bf(v.y), f2bf(v.z), f2bf(v.w) };
    reinterpret_cast<s16x4*>(out)[i] = r;
}

#define LDP 72

// ---------------- QKV GEMM (+RoPE), 256x256, 4-phase/K-tile, deep-prefetch vmcnt -----
// Waits target loads issued >=3 phases earlier:
//   stage t+1 fully in ph1/ph2 order [A0,A2,B0,B1 | B2,B3,A1,A3];
//   ph2-end: vmcnt(8) -> tile t's A1,A3 (issued LAST iteration);
//   ph4-end: vmcnt(2) -> t+1's A0,A2,B0..B3 (issued ph1/ph2), A1/A3 stay in flight.
__device__ __forceinline__ void load_a(const short* __restrict__ A, int wr, int lo, int hi,
                                       int mh, bf16x8 aF[4][2]) {
#pragma unroll
    for (int mi = 0; mi < 4; ++mi)
#pragma unroll
        for (int kk = 0; kk < 2; ++kk)
            aF[mi][kk] = *reinterpret_cast<const bf16x8*>(
                &A[(wr * 128 + mh * 64 + mi * 16 + lo) * 64 + (((kk * 4 + hi) ^ (lo & 7)) << 3)]);
}
__device__ __forceinline__ void load_b(const short* __restrict__ B, int wc, int lo, int hi,
                                       int nh, bf16x8 bFh[2][2]) {
#pragma unroll
    for (int ni = 0; ni < 2; ++ni)
#pragma unroll
        for (int kk = 0; kk < 2; ++kk)
            bFh[ni][kk] = *reinterpret_cast<const bf16x8*>(
                &B[(wc * 64 + (nh * 2 + ni) * 16 + lo) * 64 + (((kk * 4 + hi) ^ (lo & 7)) << 3)]);
}
__device__ __forceinline__ void mfma16(const bf16x8 aF[4][2], const bf16x8 bFh[2][2],
                                       f32x4 acc[8][4], int mh, int nh) {
    __builtin_amdgcn_s_setprio(1);
#pragma unroll
    for (int mi = 0; mi < 4; ++mi)
#pragma unroll
        for (int ni = 0; ni < 2; ++ni)
#pragma unroll
            for (int kk = 0; kk < 2; ++kk)
                acc[mh * 4 + mi][nh * 2 + ni] = __builtin_amdgcn_mfma_f32_16x16x32_bf16(
                    aF[mi][kk], bFh[ni][kk], acc[mh * 4 + mi][nh * 2 + ni], 0, 0, 0);
    __builtin_amdgcn_s_setprio(0);
}

__global__ __launch_bounds__(512, 1) void gemm_qkv_rope(
    const short* __restrict__ X, const short* __restrict__ W,
    const float* __restrict__ cosT, const float* __restrict__ sinT,
    short* __restrict__ Qo, short* __restrict__ Ko, short* __restrict__ Vo) {
    __shared__ short lds[2][2][16384];   // 128KB
    const int tid = threadIdx.x;
    const int lane = tid & 63;
    const int w = tid >> 6;              // 0..7
    const int lo = lane & 15, hi = lane >> 4;
    const int wr = w >> 2, wc = w & 3;   // 2 (M) x 4 (N) waves
    // XCD-chunked 2D swizzle: 4(M) x 2(N) grid of XCD chunks; live set ~5MB/XCD ~= L2.
    const int lin = blockIdx.x;
    const int xcd = lin & 7;
    const int i_ = lin >> 3;             // 0..23
    const int m0 = ((xcd >> 1) * 4 + (i_ & 3)) * 256;
    const int n0 = ((xcd & 1) * 6 + (i_ >> 2)) * 256;

    f32x4 acc[8][4];
#pragma unroll
    for (int i = 0; i < 8; i++)
#pragma unroll
        for (int j = 0; j < 4; j++) acc[i][j] = {0.f, 0.f, 0.f, 0.f};

    // staging: chunk IT covers rows IT*64 + w*8 + (lane>>3); source pre-swizzled (T2)
    const int srow8 = w * 8 + (lane >> 3);
    const int scx = (((lane & 7) ^ ((lane >> 3) & 7)) << 3);

#define STAGE_A(BUF, KT, IT) GLDS(X + (size_t)(m0 + (IT) * 64 + srow8) * 1024 + (((KT) & 15) << 6) + scx, \
                                  (char*)&lds[BUF][0][0] + (IT) * 8192 + w * 1024)
#define STAGE_B(BUF, KT, IT) GLDS(W + (size_t)(n0 + (IT) * 64 + srow8) * 1024 + (((KT) & 15) << 6) + scx, \
                                  (char*)&lds[BUF][1][0] + (IT) * 8192 + w * 1024)

    bf16x8 aF[4][2], bF[2][2][2];

    // prologue: stage tile0 -> buf0, order [A0,A2,B0..B3, A1,A3]
    STAGE_A(0, 0, 0); STAGE_A(0, 0, 2);
    STAGE_B(0, 0, 0); STAGE_B(0, 0, 1); STAGE_B(0, 0, 2); STAGE_B(0, 0, 3);
    STAGE_A(0, 0, 1); STAGE_A(0, 0, 3);
    VMC2(); BARSB();

    for (int t = 0; t < 15; ++t) {
        const int c = t & 1, nb_ = c ^ 1, t1 = t + 1;
        // ---- ph1: compute (mh0,nh0); stage t+1 first 4 chunks ----
        load_a(&lds[c][0][0], wr, lo, hi, 0, aF);
        load_b(&lds[c][1][0], wc, lo, hi, 0, bF[0]);
        STAGE_A(nb_, t1, 0); STAGE_A(nb_, t1, 2); STAGE_B(nb_, t1, 0); STAGE_B(nb_, t1, 1);
        BARSB(); LGKM0();
        mfma16(aF, bF[0], acc, 0, 0);
        BARSB();
        // ---- ph2: compute (mh0,nh1); stage t+1 last 4 chunks ----
        load_b(&lds[c][1][0], wc, lo, hi, 1, bF[1]);
        STAGE_B(nb_, t1, 2); STAGE_B(nb_, t1, 3); STAGE_A(nb_, t1, 1); STAGE_A(nb_, t1, 3);
        BARSB(); LGKM0();
        mfma16(aF, bF[1], acc, 0, 1);
        VMC8(); BARSB();   // tile t's A1,A3 landed (issued last iteration)
        // ---- ph3: compute (mh1,nh0) ----
        load_a(&lds[c][0][0], wr, lo, hi, 1, aF);
        BARSB(); LGKM0();
        mfma16(aF, bF[0], acc, 1, 0);
        BARSB();
        // ---- ph4: compute (mh1,nh1); counted wait on t+1's first 6 ----
        mfma16(aF, bF[1], acc, 1, 1);
        VMC2(); BARSB();
    }
    // ---- final tile t=15 in buf1, no staging ----
    {
        load_a(&lds[1][0][0], wr, lo, hi, 0, aF);
        load_b(&lds[1][1][0], wc, lo, hi, 0, bF[0]);
        BARSB(); LGKM0();
        mfma16(aF, bF[0], acc, 0, 0);
        BARSB();
        load_b(&lds[1][1][0], wc, lo, hi, 1, bF[1]);
        BARSB(); LGKM0();
        mfma16(aF, bF[1], acc, 0, 1);
        VMC0(); BARSB();   // tile15's A1,A3 fully landed
        load_a(&lds[1][0][0], wr, lo, hi, 1, aF);
        LGKM0();
        mfma16(aF, bF[0], acc, 1, 0);
        mfma16(aF, bF[1], acc, 1, 1);
    }
#undef STAGE_A
#undef STAGE_B

    const int region = n0 >> 10;  // 0=q, 1=k, 2=v
#pragma unroll
    for (int mi = 0; mi < 8; mi++) {
#pragma unroll
        for (int r = 0; r < 4; r++) {
            const int m = m0 + wr * 128 + mi * 16 + (hi << 2) + r;
            const int b_ = m >> 11;
            const int s_ = m & 2047;
#pragma unroll
            for (int ni = 0; ni < 4; ni++) {
                float v = acc[mi][ni][r];
                const int n = n0 + wc * 64 + ni * 16 + lo;
                const int c = n & 1023;
                const int h = c >> 6;
                const int d = c & 63;
                const size_t oidx = ((size_t)(b_ * 16 + h) * 2048 + s_) * 64 + d;
                if (region == 2) {
                    Vo[oidx] = f2bf(v);
                } else {
                    float other = __shfl_xor(v, 1, 64);
                    const int i2 = d >> 1;
                    float cs = cosT[s_ * 32 + i2];
                    float sn = sinT[s_ * 32 + i2];
                    float outv = (d & 1) ? (v * cs + other * sn) : (v * cs - other * sn);
                    if (region == 0) {
                        Qo[oidx] = f2bf(outv * 0.125f);
                    } else {
                        Ko[oidx] = f2bf(outv);
                    }
                }
            }
        }
    }
}

// ---------------- Flash attention (causal, paired q-tiles, swapped QK^T, dbuf) -------
__device__ __forceinline__ void attn_tile_compute(
    const bf16x8 q0, const bf16x8 q1,
    const short (*Ks)[LDP], const short (*Vts)[LDP], short* __restrict__ Pw,
    const int lane, const int w, const bool diag,
    float& m_r, float& l_r, f32x4* __restrict__ o_acc) {
    const int lo = lane & 15, hi = lane >> 4;

    f32x4 sc[4];
#pragma unroll
    for (int nb = 0; nb < 4; nb++) sc[nb] = {0.f, 0.f, 0.f, 0.f};
#pragma unroll
    for (int nb = 0; nb < 4; nb++) {
        bf16x8 k0 = *reinterpret_cast<const bf16x8*>(&Ks[nb * 16 + lo][hi * 8]);
        sc[nb] = __builtin_amdgcn_mfma_f32_16x16x32_bf16(k0, q0, sc[nb], 0, 0, 0);
        bf16x8 k1 = *reinterpret_cast<const bf16x8*>(&Ks[nb * 16 + lo][32 + hi * 8]);
        sc[nb] = __builtin_amdgcn_mfma_f32_16x16x32_bf16(k1, q1, sc[nb], 0, 0, 0);
    }
    if (diag) {
        const int q_ = w * 16 + lo;
        const int kb = (hi << 2);
#pragma unroll
        for (int nb = 0; nb < 4; nb++) {
            const int k_ = nb * 16 + kb;
#pragma unroll
            for (int r = 0; r < 4; r++)
                if (k_ + r > q_) sc[nb][r] = -1e30f;
        }
    }

    float mx = sc[0][0];
#pragma unroll
    for (int nb = 0; nb < 4; nb++)
#pragma unroll
        for (int r = 0; r < 4; r++) mx = fmaxf(mx, sc[nb][r]);
    mx = fmaxf(mx, __shfl_xor(mx, 16, 64));
    mx = fmaxf(mx, __shfl_xor(mx, 32, 64));

    const float mnew = fmaxf(m_r, mx);
    const float alpha = __expf(m_r - mnew);
    m_r = mnew;

    float rs = 0.f;
#pragma unroll
    for (int nb = 0; nb < 4; nb++)
#pragma unroll
        for (int r = 0; r < 4; r++) {
            float e = __expf(sc[nb][r] - mnew);
            sc[nb][r] = e;
            rs += e;
        }
    rs += __shfl_xor(rs, 16, 64);
    rs += __shfl_xor(rs, 32, 64);
    l_r = l_r * alpha + rs;

    float alpha_q[4];
#pragma unroll
    for (int r = 0; r < 4; r++) alpha_q[r] = __shfl(alpha, (hi << 2) + r, 64);
#pragma unroll
    for (int db = 0; db < 4; db++)
#pragma unroll
        for (int r = 0; r < 4; r++) o_acc[db][r] *= alpha_q[r];

    unsigned int* Pw32 = reinterpret_cast<unsigned int*>(Pw);
#pragma unroll
    for (int nb = 0; nb < 4; nb++)
#pragma unroll
        for (int rr = 0; rr < 2; rr++) {
            unsigned int u = (unsigned int)(unsigned short)f2bf(sc[nb][2 * rr]) |
                             ((unsigned int)(unsigned short)f2bf(sc[nb][2 * rr + 1]) << 16);
            Pw32[lo * (LDP / 2) + nb * 8 + (hi << 1) + rr] = u;
        }

#pragma unroll
    for (int kk = 0; kk < 2; kk++) {
        bf16x8 pa = *reinterpret_cast<const bf16x8*>(&Pw[lo * LDP + kk * 32 + hi * 8]);
#pragma unroll
        for (int db = 0; db < 4; db++) {
            const int d = db * 16 + lo;
            const int tsw = (kk * 32 + hi * 8) ^ ((((d >> 3) & 7)) << 3);
            bf16x8 vb = *reinterpret_cast<const bf16x8*>(&Vts[d][tsw]);
            o_acc[db] = __builtin_amdgcn_mfma_f32_16x16x32_bf16(pa, vb, o_acc[db], 0, 0, 0);
        }
    }
}

__global__ __launch_bounds__(256) void attn_kernel(
    const short* __restrict__ Q, const short* __restrict__ K,
    const short* __restrict__ V, short* __restrict__ O) {
    __shared__ short Ks[2][64][LDP];
    __shared__ short Vts[2][64][LDP];
    __shared__ short Ps[4][16][LDP];

    const int tid = threadIdx.x;
    const int lane = tid & 63;
    const int w = tid >> 6;
    const int lo = lane & 15, hi = lane >> 4;
    const int lin = blockIdx.x;
    const int wg = (lin & 7) * 64 + (lin >> 3);
    const int pi = wg & 15;
    const int bh = wg >> 4;
    const int qa = pi, qb = 31 - pi;
    const int b_ = bh >> 4, h = bh & 15;
    const size_t base = (size_t)bh * 2048 * 64;

    bf16x8 qaf0, qaf1, qbf0, qbf1;
    {
        const int row = tid >> 2, cb = (tid & 3) * 16;
        const short* srcA = Q + base + (size_t)(qa * 64 + row) * 64 + cb;
        *reinterpret_cast<bf16x8*>(&Ks[0][row][cb]) = *reinterpret_cast<const bf16x8*>(srcA);
        *reinterpret_cast<bf16x8*>(&Ks[0][row][cb + 8]) = *reinterpret_cast<const bf16x8*>(srcA + 8);
        __syncthreads();
        qaf0 = *reinterpret_cast<const bf16x8*>(&Ks[0][w * 16 + lo][hi * 8]);
        qaf1 = *reinterpret_cast<const bf16x8*>(&Ks[0][w * 16 + lo][32 + hi * 8]);
        __syncthreads();
        const short* srcB = Q + base + (size_t)(qb * 64 + row) * 64 + cb;
        *reinterpret_cast<bf16x8*>(&Ks[0][row][cb]) = *reinterpret_cast<const bf16x8*>(srcB);
        *reinterpret_cast<bf16x8*>(&Ks[0][row][cb + 8]) = *reinterpret_cast<const bf16x8*>(srcB + 8);
        __syncthreads();
        qbf0 = *reinterpret_cast<const bf16x8*>(&Ks[0][w * 16 + lo][hi * 8]);
        qbf1 = *reinterpret_cast<const bf16x8*>(&Ks[0][w * 16 + lo][32 + hi * 8]);
        __syncthreads();
    }

    float m_a = -1e30f, l_a = 0.f, m_b = -1e30f, l_b = 0.f;
    f32x4 o_a[4], o_b[4];
#pragma unroll
    for (int db = 0; db < 4; db++) { o_a[db] = {0.f, 0.f, 0.f, 0.f}; o_b[db] = {0.f, 0.f, 0.f, 0.f}; }

    const int krow = tid >> 2, kcb = (tid & 3) * 16;
    const int vkv = tid >> 3, vdb8 = (tid & 7) * 8;
    const int vswz = (tid & 7) << 3;
    bf16x8 kr0, kr1, vr0, vr1;
    kr0 = *reinterpret_cast<const bf16x8*>(K + base + (size_t)krow * 64 + kcb);
    kr1 = *reinterpret_cast<const bf16x8*>(K + base + (size_t)krow * 64 + kcb + 8);
    vr0 = *reinterpret_cast<const bf16x8*>(V + base + (size_t)vkv * 64 + vdb8);
    vr1 = *reinterpret_cast<const bf16x8*>(V + base + (size_t)(vkv + 32) * 64 + vdb8);

    int c = 0;
    for (int j = 0; j <= qb; j++) {
        *reinterpret_cast<bf16x8*>(&Ks[c][krow][kcb]) = kr0;
        *reinterpret_cast<bf16x8*>(&Ks[c][krow][kcb + 8]) = kr1;
        {
            const int t0 = vkv ^ vswz;
            const int t1 = (vkv + 32) ^ vswz;
#pragma unroll
            for (int i = 0; i < 8; i++) Vts[c][vdb8 + i][t0] = vr0[i];
#pragma unroll
            for (int i = 0; i < 8; i++) Vts[c][vdb8 + i][t1] = vr1[i];
        }
        __syncthreads();
        if (j < qb) {
            const size_t jb2 = (size_t)(j + 1) * 64;
            kr0 = *reinterpret_cast<const bf16x8*>(K + base + (jb2 + krow) * 64 + kcb);
            kr1 = *reinterpret_cast<const bf16x8*>(K + base + (jb2 + krow) * 64 + kcb + 8);
            vr0 = *reinterpret_cast<const bf16x8*>(V + base + (jb2 + vkv) * 64 + vdb8);
            vr1 = *reinterpret_cast<const bf16x8*>(V + base + (jb2 + vkv + 32) * 64 + vdb8);
        }

        attn_tile_compute(qbf0, qbf1, Ks[c], Vts[c], &Ps[w][0][0], lane, w, j == qb, m_b, l_b, o_b);
        if (j <= qa)
            attn_tile_compute(qaf0, qaf1, Ks[c], Vts[c], &Ps[w][0][0], lane, w, j == qa, m_a, l_a, o_a);
        c ^= 1;
    }

    float inva[4], invb[4];
#pragma unroll
    for (int r = 0; r < 4; r++) {
        inva[r] = 1.f / __shfl(l_a, (hi << 2) + r, 64);
        invb[r] = 1.f / __shfl(l_b, (hi << 2) + r, 64);
    }

    short* Op = O + ((size_t)b_ * 2048) * 1024 + (size_t)h * 64;
#pragma unroll
    for (int r = 0; r < 4; r++) {
        const int rowa = qa * 64 + w * 16 + (hi << 2) + r;
        const int rowb = qb * 64 + w * 16 + (hi << 2) + r;
#pragma unroll
        for (int db = 0; db < 4; db++) {
            Op[(size_t)rowa * 1024 + db * 16 + lo] = f2bf(o_a[db][r] * inva[r]);
            Op[(size_t)rowb * 1024 + db * 16 + lo] = f2bf(o_b[db][r] * invb[r]);
        }
    }
}

// ---------------- Out GEMM, 128x128, dbuf prefetch 2-phase, XCD swizzle --------------
__global__ __launch_bounds__(256) void gemm_out(
    const short* __restrict__ A, const short* __restrict__ W,
    float* __restrict__ C) {
    __shared__ short As[2][128 * 64];
    __shared__ short Bs[2][128 * 64];
    const int tid = threadIdx.x;
    const int lane = tid & 63;
    const int w = tid >> 6;
    const int lo = lane & 15, hi = lane >> 4;
    const int wr = w >> 1, wc = w & 1;
    const int lin = blockIdx.x;
    const int wg = (lin & 7) * 32 + (lin >> 3);
    const int n0 = (wg & 7) * 128;
    const int m0 = (wg >> 3) * 128;
    const int K = 1024;

    f32x4 acc[4][4];
#pragma unroll
    for (int i = 0; i < 4; i++)
#pragma unroll
        for (int j = 0; j < 4; j++) acc[i][j] = {0.f, 0.f, 0.f, 0.f};

    const int srow = w * 8 + (lane >> 3);
    const int sc8 = (lane & 7) * 8;
    const short* gA = A + (size_t)(m0 + srow) * K + sc8;
    const short* gB = W + (size_t)(n0 + srow) * K + sc8;

#pragma unroll
    for (int it = 0; it < 4; it++)
        GLDS(gA + (size_t)it * 32 * K, (char*)As[0] + it * 4096 + w * 1024);
#pragma unroll
    for (int it = 0; it < 4; it++)
        GLDS(gB + (size_t)it * 32 * K, (char*)Bs[0] + it * 4096 + w * 1024);
    __syncthreads();

    int cur = 0;
    for (int t = 0; t < 16; t++) {
        if (t < 15) {
            const int k1 = (t + 1) * 64;
#pragma unroll
            for (int it = 0; it < 4; it++)
                GLDS(gA + k1 + (size_t)it * 32 * K, (char*)As[cur ^ 1] + it * 4096 + w * 1024);
#pragma unroll
            for (int it = 0; it < 4; it++)
                GLDS(gB + k1 + (size_t)it * 32 * K, (char*)Bs[cur ^ 1] + it * 4096 + w * 1024);
        }
#pragma unroll
        for (int kk = 0; kk < 2; kk++) {
            bf16x8 a[4], b[4];
#pragma unroll
            for (int mi = 0; mi < 4; mi++)
                a[mi] = *reinterpret_cast<const bf16x8*>(
                    &As[cur][(wr * 64 + mi * 16 + lo) * 64 + kk * 32 + hi * 8]);
#pragma unroll
            for (int ni = 0; ni < 4; ni++)
                b[ni] = *reinterpret_cast<const bf16x8*>(
                    &Bs[cur][(wc * 64 + ni * 16 + lo) * 64 + kk * 32 + hi * 8]);
#pragma unroll
            for (int mi = 0; mi < 4; mi++)
#pragma unroll
                for (int ni = 0; ni < 4; ni++)
                    acc[mi][ni] = __builtin_amdgcn_mfma_f32_16x16x32_bf16(
                        a[mi], b[ni], acc[mi][ni], 0, 0, 0);
        }
        if (t < 15) __syncthreads();
        cur ^= 1;
    }

#pragma unroll
    for (int mi = 0; mi < 4; mi++) {
#pragma unroll
        for (int r = 0; r < 4; r++) {
            const int m = m0 + wr * 64 + mi * 16 + (hi << 2) + r;
#pragma unroll
            for (int ni = 0; ni < 4; ni++) {
                const int n = n0 + wc * 64 + ni * 16 + lo;
                C[(size_t)m * 1024 + n] = acc[mi][ni][r];
            }
        }
    }
}

extern "C" void kernel_launch(void* const* d_in, const int* in_sizes, int n_in,
                              void* d_out, int out_size, void* d_ws, size_t ws_size,
                              hipStream_t stream) {
    const float* x = (const float*)d_in[0];
    const float* wQKV = (const float*)d_in[1];
    const float* wOut = (const float*)d_in[2];
    const float* cosT = (const float*)d_in[3];
    const float* sinT = (const float*)d_in[4];
    float* out = (float*)d_out;

    char* ws = (char*)d_ws;
    const size_t MB = 1024 * 1024;
    short* xb    = (short*)(ws);             // 8MB
    short* wqkvb = (short*)(ws + 8 * MB);    // 6MB
    short* woutb = (short*)(ws + 14 * MB);   // 2MB
    short* Qbuf  = (short*)(ws + 16 * MB);   // 8MB
    short* Kbuf  = (short*)(ws + 24 * MB);   // 8MB
    short* Vbuf  = (short*)(ws + 32 * MB);   // 8MB
    short* Obuf  = (short*)(ws + 40 * MB);   // 8MB (attn out, bf16)

    cvt_kernel<<<4096, 256, 0, stream>>>(x, xb, 1048576);
    cvt_kernel<<<3072, 256, 0, stream>>>(wQKV, wqkvb, 786432);
    cvt_kernel<<<1024, 256, 0, stream>>>(wOut, woutb, 262144);

    gemm_qkv_rope<<<192, 512, 0, stream>>>(xb, wqkvb, cosT, sinT, Qbuf, Kbuf, Vbuf);
    attn_kernel<<<512, 256, 0, stream>>>(Qbuf, Kbuf, Vbuf, Obuf);
    gemm_out<<<256, 256, 0, stream>>>(Obuf, woutb, out);
}

// Round 11
// 136.531 us; speedup vs baseline: 1.1009x; 1.1009x over previous
//
#include <hip/hip_runtime.h>
#include <hip/hip_bf16.h>

typedef __attribute__((ext_vector_type(8))) short bf16x8;
typedef __attribute__((ext_vector_type(4))) short s16x4;
typedef __attribute__((ext_vector_type(4))) float f32x4;

__device__ __forceinline__ short f2bf(float f) {
    unsigned int u = __builtin_bit_cast(unsigned int, f);
    u += 0x7fffu + ((u >> 16) & 1u);
    return (short)(u >> 16);
}

#define GLDS(g, l) __builtin_amdgcn_global_load_lds( \
    (__attribute__((address_space(1))) void*)(g),    \
    (__attribute__((address_space(3))) void*)(l), 16, 0, 0)

#define BARSB() { __builtin_amdgcn_s_barrier(); __builtin_amdgcn_sched_barrier(0); }
#define LGKM0() { asm volatile("s_waitcnt lgkmcnt(0)" ::: "memory"); __builtin_amdgcn_sched_barrier(0); }
#define VMC7()  { asm volatile("s_waitcnt vmcnt(7)" ::: "memory"); __builtin_amdgcn_sched_barrier(0); }
#define VMC2()  { asm volatile("s_waitcnt vmcnt(2)" ::: "memory"); __builtin_amdgcn_sched_barrier(0); }
#define VMC0()  { asm volatile("s_waitcnt vmcnt(0)" ::: "memory"); __builtin_amdgcn_sched_barrier(0); }

// ---------------- fp32 -> bf16 convert ----------------
__global__ __launch_bounds__(256) void cvt_kernel(const float* __restrict__ in,
                                                  short* __restrict__ out, int n4) {
    int i = blockIdx.x * 256 + threadIdx.x;
    if (i >= n4) return;
    float4 v = reinterpret_cast<const float4*>(in)[i];
    s16x4 r = { f2bf(v.x), f2bf(v.y), f2bf(v.z), f2bf(v.w) };
    reinterpret_cast<s16x4*>(out)[i] = r;
}

#define LDP 72

// ---------------- QKV GEMM (+RoPE), 256x192 tile, 256 blocks (full CU coverage) ------
// LDS: A [256][64], B [192][64], both double-buffered; chunk swizzle (T2) both sides.
__device__ __forceinline__ void load_a(const short* __restrict__ A, int wr, int lo, int hi,
                                       int mh, bf16x8 aF[4][2]) {
#pragma unroll
    for (int mi = 0; mi < 4; ++mi)
#pragma unroll
        for (int kk = 0; kk < 2; ++kk)
            aF[mi][kk] = *reinterpret_cast<const bf16x8*>(
                &A[(wr * 128 + mh * 64 + mi * 16 + lo) * 64 + (((kk * 4 + hi) ^ (lo & 7)) << 3)]);
}
__device__ __forceinline__ void load_b3(const short* __restrict__ B, int wc, int lo, int hi,
                                        bf16x8 bF[3][2]) {
#pragma unroll
    for (int ni = 0; ni < 3; ++ni)
#pragma unroll
        for (int kk = 0; kk < 2; ++kk)
            bF[ni][kk] = *reinterpret_cast<const bf16x8*>(
                &B[(wc * 48 + ni * 16 + lo) * 64 + (((kk * 4 + hi) ^ (lo & 7)) << 3)]);
}
__device__ __forceinline__ void mfma24(const bf16x8 aF[4][2], const bf16x8 bF[3][2],
                                       f32x4 acc[8][3], int mh) {
#pragma unroll
    for (int mi = 0; mi < 4; ++mi)
#pragma unroll
        for (int ni = 0; ni < 3; ++ni)
#pragma unroll
            for (int kk = 0; kk < 2; ++kk)
                acc[mh * 4 + mi][ni] = __builtin_amdgcn_mfma_f32_16x16x32_bf16(
                    aF[mi][kk], bF[ni][kk], acc[mh * 4 + mi][ni], 0, 0, 0);
}

__global__ __launch_bounds__(512, 1) void gemm_qkv_rope(
    const short* __restrict__ X, const short* __restrict__ W,
    const float* __restrict__ cosT, const float* __restrict__ sinT,
    short* __restrict__ Qo, short* __restrict__ Ko, short* __restrict__ Vo) {
    __shared__ short ldsA[2][16384];   // 2 x 32KB
    __shared__ short ldsB[2][12288];   // 2 x 24KB
    const int tid = threadIdx.x;
    const int lane = tid & 63;
    const int w = tid >> 6;              // 0..7
    const int lo = lane & 15, hi = lane >> 4;
    const int wr = w >> 2, wc = w & 3;   // 2 (M) x 4 (N) waves; per-wave 128x48
    // XCD 2D chunking: 8 XCDs as 4(M) x 2(N); 32 blocks/XCD span 4 m- x 8 n-panels.
    const int lin = blockIdx.x;
    const int xcd = lin & 7;
    const int i_ = lin >> 3;             // 0..31
    const int m0 = ((xcd >> 1) * 4 + (i_ & 3)) * 256;
    const int n0 = ((xcd & 1) * 8 + (i_ >> 2)) * 192;

    f32x4 acc[8][3];
#pragma unroll
    for (int i = 0; i < 8; i++)
#pragma unroll
        for (int j = 0; j < 3; j++) acc[i][j] = {0.f, 0.f, 0.f, 0.f};

    // staging: chunk IT covers rows IT*64 + w*8 + (lane>>3); src pre-swizzled (T2)
    const int srow8 = w * 8 + (lane >> 3);
    const int scx = (((lane & 7) ^ ((lane >> 3) & 7)) << 3);

#define STAGE_A(BUF, KT, IT) GLDS(X + (size_t)(m0 + (IT) * 64 + srow8) * 1024 + ((KT) << 6) + scx, \
                                  (char*)&ldsA[BUF][0] + (IT) * 8192 + w * 1024)
#define STAGE_B(BUF, KT, IT) GLDS(W + (size_t)(n0 + (IT) * 64 + srow8) * 1024 + ((KT) << 6) + scx, \
                                  (char*)&ldsB[BUF][0] + (IT) * 8192 + w * 1024)

    bf16x8 aF[4][2], bF[3][2];

    // prologue: tile0 -> buf0, order [B0,B1,B2,A0,A2, A1,A3]; wait first 5
    STAGE_B(0, 0, 0); STAGE_B(0, 0, 1); STAGE_B(0, 0, 2);
    STAGE_A(0, 0, 0); STAGE_A(0, 0, 2);
    STAGE_A(0, 0, 1); STAGE_A(0, 0, 3);
    VMC2(); BARSB();

    for (int t = 0; t < 15; ++t) {
        const int c = t & 1, nb_ = c ^ 1, t1 = t + 1;
        // ---- phase A: compute mh0 x all ni; stage t+1 ----
        load_a(&ldsA[c][0], wr, lo, hi, 0, aF);
        load_b3(&ldsB[c][0], wc, lo, hi, bF);
        STAGE_B(nb_, t1, 0); STAGE_B(nb_, t1, 1); STAGE_B(nb_, t1, 2); STAGE_A(nb_, t1, 0);
        BARSB(); LGKM0();
        mfma24(aF, bF, acc, 0);
        STAGE_A(nb_, t1, 2); STAGE_A(nb_, t1, 1); STAGE_A(nb_, t1, 3);
        VMC7(); BARSB();   // tile t's A1,A3 landed (issued last iteration)
        // ---- phase B: compute mh1 x all ni; counted wait on t+1's first 5 ----
        load_a(&ldsA[c][0], wr, lo, hi, 1, aF);
        BARSB(); LGKM0();
        mfma24(aF, bF, acc, 1);
        VMC2(); BARSB();
    }
    // ---- final tile t=15 in buf1, no staging ----
    {
        load_a(&ldsA[1][0], wr, lo, hi, 0, aF);
        load_b3(&ldsB[1][0], wc, lo, hi, bF);
        BARSB(); LGKM0();
        mfma24(aF, bF, acc, 0);
        VMC0(); BARSB();   // tile15's A1,A3 fully landed
        load_a(&ldsA[1][0], wr, lo, hi, 1, aF);
        LGKM0();
        mfma24(aF, bF, acc, 1);
    }
#undef STAGE_A
#undef STAGE_B

#pragma unroll
    for (int mi = 0; mi < 8; mi++) {
#pragma unroll
        for (int r = 0; r < 4; r++) {
            const int m = m0 + wr * 128 + mi * 16 + (hi << 2) + r;
            const int b_ = m >> 11;
            const int s_ = m & 2047;
#pragma unroll
            for (int ni = 0; ni < 3; ni++) {
                float v = acc[mi][ni][r];
                const int n = n0 + wc * 48 + ni * 16 + lo;
                const int region = n >> 10;      // wave-uniform per ni (16 | 1024)
                const int c = n & 1023;
                const int h = c >> 6;
                const int d = c & 63;
                const size_t oidx = ((size_t)(b_ * 16 + h) * 2048 + s_) * 64 + d;
                if (region == 2) {
                    Vo[oidx] = f2bf(v);
                } else {
                    float other = __shfl_xor(v, 1, 64);
                    const int i2 = d >> 1;
                    float cs = cosT[s_ * 32 + i2];
                    float sn = sinT[s_ * 32 + i2];
                    float outv = (d & 1) ? (v * cs + other * sn) : (v * cs - other * sn);
                    if (region == 0) {
                        Qo[oidx] = f2bf(outv * 0.125f);
                    } else {
                        Ko[oidx] = f2bf(outv);
                    }
                }
            }
        }
    }
}

// ---------------- Flash attention (causal, 1 q-tile/block, LPT order, 3 blocks/CU) ---
__device__ __forceinline__ void attn_tile_compute(
    const bf16x8 q0, const bf16x8 q1,
    const short (*Ks)[LDP], const short (*Vts)[LDP], short* __restrict__ Pw,
    const int lane, const int w, const bool diag,
    float& m_r, float& l_r, f32x4* __restrict__ o_acc) {
    const int lo = lane & 15, hi = lane >> 4;

    f32x4 sc[4];
#pragma unroll
    for (int nb = 0; nb < 4; nb++) sc[nb] = {0.f, 0.f, 0.f, 0.f};
#pragma unroll
    for (int nb = 0; nb < 4; nb++) {
        bf16x8 k0 = *reinterpret_cast<const bf16x8*>(&Ks[nb * 16 + lo][hi * 8]);
        sc[nb] = __builtin_amdgcn_mfma_f32_16x16x32_bf16(k0, q0, sc[nb], 0, 0, 0);
        bf16x8 k1 = *reinterpret_cast<const bf16x8*>(&Ks[nb * 16 + lo][32 + hi * 8]);
        sc[nb] = __builtin_amdgcn_mfma_f32_16x16x32_bf16(k1, q1, sc[nb], 0, 0, 0);
    }
    if (diag) {
        const int q_ = w * 16 + lo;
        const int kb = (hi << 2);
#pragma unroll
        for (int nb = 0; nb < 4; nb++) {
            const int k_ = nb * 16 + kb;
#pragma unroll
            for (int r = 0; r < 4; r++)
                if (k_ + r > q_) sc[nb][r] = -1e30f;
        }
    }

    float mx = sc[0][0];
#pragma unroll
    for (int nb = 0; nb < 4; nb++)
#pragma unroll
        for (int r = 0; r < 4; r++) mx = fmaxf(mx, sc[nb][r]);
    mx = fmaxf(mx, __shfl_xor(mx, 16, 64));
    mx = fmaxf(mx, __shfl_xor(mx, 32, 64));

    const float mnew = fmaxf(m_r, mx);
    const float alpha = __expf(m_r - mnew);
    m_r = mnew;

    float rs = 0.f;
#pragma unroll
    for (int nb = 0; nb < 4; nb++)
#pragma unroll
        for (int r = 0; r < 4; r++) {
            float e = __expf(sc[nb][r] - mnew);
            sc[nb][r] = e;
            rs += e;
        }
    rs += __shfl_xor(rs, 16, 64);
    rs += __shfl_xor(rs, 32, 64);
    l_r = l_r * alpha + rs;

    float alpha_q[4];
#pragma unroll
    for (int r = 0; r < 4; r++) alpha_q[r] = __shfl(alpha, (hi << 2) + r, 64);
#pragma unroll
    for (int db = 0; db < 4; db++)
#pragma unroll
        for (int r = 0; r < 4; r++) o_acc[db][r] *= alpha_q[r];

    unsigned int* Pw32 = reinterpret_cast<unsigned int*>(Pw);
#pragma unroll
    for (int nb = 0; nb < 4; nb++)
#pragma unroll
        for (int rr = 0; rr < 2; rr++) {
            unsigned int u = (unsigned int)(unsigned short)f2bf(sc[nb][2 * rr]) |
                             ((unsigned int)(unsigned short)f2bf(sc[nb][2 * rr + 1]) << 16);
            Pw32[lo * (LDP / 2) + nb * 8 + (hi << 1) + rr] = u;
        }

#pragma unroll
    for (int kk = 0; kk < 2; kk++) {
        bf16x8 pa = *reinterpret_cast<const bf16x8*>(&Pw[lo * LDP + kk * 32 + hi * 8]);
#pragma unroll
        for (int db = 0; db < 4; db++) {
            const int d = db * 16 + lo;
            const int tsw = (kk * 32 + hi * 8) ^ ((((d >> 3) & 7)) << 3);
            bf16x8 vb = *reinterpret_cast<const bf16x8*>(&Vts[d][tsw]);
            o_acc[db] = __builtin_amdgcn_mfma_f32_16x16x32_bf16(pa, vb, o_acc[db], 0, 0, 0);
        }
    }
}

__global__ __launch_bounds__(256) void attn_kernel(
    const short* __restrict__ Q, const short* __restrict__ K,
    const short* __restrict__ V, short* __restrict__ O) {
    __shared__ short Ks[2][64][LDP];
    __shared__ short Vts[2][64][LDP];
    __shared__ short Ps[4][16][LDP];   // 45KB total -> 3 blocks/CU

    const int tid = threadIdx.x;
    const int lane = tid & 63;
    const int w = tid >> 6;
    const int lo = lane & 15, hi = lane >> 4;
    // LPT order (heavy first) + XCD = bh%8 (32%8==0): lin = qtOrd*32 + bh
    const int lin = blockIdx.x;
    const int bh = lin & 31;
    const int qt = 31 - (lin >> 5);
    const int b_ = bh >> 4, h = bh & 15;
    const size_t base = (size_t)bh * 2048 * 64;

    // Q-hoist: stage Q tile through Ks[0], keep fragments in registers
    bf16x8 q0, q1;
    {
        const int row = tid >> 2, cb = (tid & 3) * 16;
        const short* src = Q + base + (size_t)(qt * 64 + row) * 64 + cb;
        *reinterpret_cast<bf16x8*>(&Ks[0][row][cb]) = *reinterpret_cast<const bf16x8*>(src);
        *reinterpret_cast<bf16x8*>(&Ks[0][row][cb + 8]) = *reinterpret_cast<const bf16x8*>(src + 8);
        __syncthreads();
        q0 = *reinterpret_cast<const bf16x8*>(&Ks[0][w * 16 + lo][hi * 8]);
        q1 = *reinterpret_cast<const bf16x8*>(&Ks[0][w * 16 + lo][32 + hi * 8]);
        __syncthreads();
    }

    float m_r = -1e30f, l_r = 0.f;
    f32x4 o_acc[4];
#pragma unroll
    for (int db = 0; db < 4; db++) o_acc[db] = {0.f, 0.f, 0.f, 0.f};

    // register prefetch of tile j=0
    const int krow = tid >> 2, kcb = (tid & 3) * 16;
    const int vkv = tid >> 3, vdb8 = (tid & 7) * 8;
    const int vswz = (tid & 7) << 3;
    bf16x8 kr0, kr1, vr0, vr1;
    kr0 = *reinterpret_cast<const bf16x8*>(K + base + (size_t)krow * 64 + kcb);
    kr1 = *reinterpret_cast<const bf16x8*>(K + base + (size_t)krow * 64 + kcb + 8);
    vr0 = *reinterpret_cast<const bf16x8*>(V + base + (size_t)vkv * 64 + vdb8);
    vr1 = *reinterpret_cast<const bf16x8*>(V + base + (size_t)(vkv + 32) * 64 + vdb8);

    int c = 0;
    for (int j = 0; j <= qt; j++) {
        *reinterpret_cast<bf16x8*>(&Ks[c][krow][kcb]) = kr0;
        *reinterpret_cast<bf16x8*>(&Ks[c][krow][kcb + 8]) = kr1;
        {
            const int t0 = vkv ^ vswz;
            const int t1 = (vkv + 32) ^ vswz;
#pragma unroll
            for (int i = 0; i < 8; i++) Vts[c][vdb8 + i][t0] = vr0[i];
#pragma unroll
            for (int i = 0; i < 8; i++) Vts[c][vdb8 + i][t1] = vr1[i];
        }
        __syncthreads();
        if (j < qt) {
            const size_t jb2 = (size_t)(j + 1) * 64;
            kr0 = *reinterpret_cast<const bf16x8*>(K + base + (jb2 + krow) * 64 + kcb);
            kr1 = *reinterpret_cast<const bf16x8*>(K + base + (jb2 + krow) * 64 + kcb + 8);
            vr0 = *reinterpret_cast<const bf16x8*>(V + base + (jb2 + vkv) * 64 + vdb8);
            vr1 = *reinterpret_cast<const bf16x8*>(V + base + (jb2 + vkv + 32) * 64 + vdb8);
        }

        attn_tile_compute(q0, q1, Ks[c], Vts[c], &Ps[w][0][0], lane, w, j == qt, m_r, l_r, o_acc);
        c ^= 1;
    }

    float inv[4];
#pragma unroll
    for (int r = 0; r < 4; r++) inv[r] = 1.f / __shfl(l_r, (hi << 2) + r, 64);

    short* Op = O + ((size_t)b_ * 2048) * 1024 + (size_t)h * 64;
#pragma unroll
    for (int r = 0; r < 4; r++) {
        const int row = qt * 64 + w * 16 + (hi << 2) + r;
#pragma unroll
        for (int db = 0; db < 4; db++)
            Op[(size_t)row * 1024 + db * 16 + lo] = f2bf(o_acc[db][r] * inv[r]);
    }
}

// ---------------- Out GEMM, 128x128, dbuf prefetch 2-phase, XCD swizzle --------------
__global__ __launch_bounds__(256) void gemm_out(
    const short* __restrict__ A, const short* __restrict__ W,
    float* __restrict__ C) {
    __shared__ short As[2][128 * 64];
    __shared__ short Bs[2][128 * 64];
    const int tid = threadIdx.x;
    const int lane = tid & 63;
    const int w = tid >> 6;
    const int lo = lane & 15, hi = lane >> 4;
    const int wr = w >> 1, wc = w & 1;
    const int lin = blockIdx.x;
    const int wg = (lin & 7) * 32 + (lin >> 3);
    const int n0 = (wg & 7) * 128;
    const int m0 = (wg >> 3) * 128;
    const int K = 1024;

    f32x4 acc[4][4];
#pragma unroll
    for (int i = 0; i < 4; i++)
#pragma unroll
        for (int j = 0; j < 4; j++) acc[i][j] = {0.f, 0.f, 0.f, 0.f};

    const int srow = w * 8 + (lane >> 3);
    const int sc8 = (lane & 7) * 8;
    const short* gA = A + (size_t)(m0 + srow) * K + sc8;
    const short* gB = W + (size_t)(n0 + srow) * K + sc8;

#pragma unroll
    for (int it = 0; it < 4; it++)
        GLDS(gA + (size_t)it * 32 * K, (char*)As[0] + it * 4096 + w * 1024);
#pragma unroll
    for (int it = 0; it < 4; it++)
        GLDS(gB + (size_t)it * 32 * K, (char*)Bs[0] + it * 4096 + w * 1024);
    __syncthreads();

    int cur = 0;
    for (int t = 0; t < 16; t++) {
        if (t < 15) {
            const int k1 = (t + 1) * 64;
#pragma unroll
            for (int it = 0; it < 4; it++)
                GLDS(gA + k1 + (size_t)it * 32 * K, (char*)As[cur ^ 1] + it * 4096 + w * 1024);
#pragma unroll
            for (int it = 0; it < 4; it++)
                GLDS(gB + k1 + (size_t)it * 32 * K, (char*)Bs[cur ^ 1] + it * 4096 + w * 1024);
        }
#pragma unroll
        for (int kk = 0; kk < 2; kk++) {
            bf16x8 a[4], b[4];
#pragma unroll
            for (int mi = 0; mi < 4; mi++)
                a[mi] = *reinterpret_cast<const bf16x8*>(
                    &As[cur][(wr * 64 + mi * 16 + lo) * 64 + kk * 32 + hi * 8]);
#pragma unroll
            for (int ni = 0; ni < 4; ni++)
                b[ni] = *reinterpret_cast<const bf16x8*>(
                    &Bs[cur][(wc * 64 + ni * 16 + lo) * 64 + kk * 32 + hi * 8]);
#pragma unroll
            for (int mi = 0; mi < 4; mi++)
#pragma unroll
                for (int ni = 0; ni < 4; ni++)
                    acc[mi][ni] = __builtin_amdgcn_mfma_f32_16x16x32_bf16(
                        a[mi], b[ni], acc[mi][ni], 0, 0, 0);
        }
        if (t < 15) __syncthreads();
        cur ^= 1;
    }

#pragma unroll
    for (int mi = 0; mi < 4; mi++) {
#pragma unroll
        for (int r = 0; r < 4; r++) {
            const int m = m0 + wr * 64 + mi * 16 + (hi << 2) + r;
#pragma unroll
            for (int ni = 0; ni < 4; ni++) {
                const int n = n0 + wc * 64 + ni * 16 + lo;
                C[(size_t)m * 1024 + n] = acc[mi][ni][r];
            }
        }
    }
}

extern "C" void kernel_launch(void* const* d_in, const int* in_sizes, int n_in,
                              void* d_out, int out_size, void* d_ws, size_t ws_size,
                              hipStream_t stream) {
    const float* x = (const float*)d_in[0];
    const float* wQKV = (const float*)d_in[1];
    const float* wOut = (const float*)d_in[2];
    const float* cosT = (const float*)d_in[3];
    const float* sinT = (const float*)d_in[4];
    float* out = (float*)d_out;

    char* ws = (char*)d_ws;
    const size_t MB = 1024 * 1024;
    short* xb    = (short*)(ws);             // 8MB
    short* wqkvb = (short*)(ws + 8 * MB);    // 6MB
    short* woutb = (short*)(ws + 14 * MB);   // 2MB
    short* Qbuf  = (short*)(ws + 16 * MB);   // 8MB
    short* Kbuf  = (short*)(ws + 24 * MB);   // 8MB
    short* Vbuf  = (short*)(ws + 32 * MB);   // 8MB
    short* Obuf  = (short*)(ws + 40 * MB);   // 8MB (attn out, bf16)

    cvt_kernel<<<4096, 256, 0, stream>>>(x, xb, 1048576);
    cvt_kernel<<<3072, 256, 0, stream>>>(wQKV, wqkvb, 786432);
    cvt_kernel<<<1024, 256, 0, stream>>>(wOut, woutb, 262144);

    gemm_qkv_rope<<<256, 512, 0, stream>>>(xb, wqkvb, cosT, sinT, Qbuf, Kbuf, Vbuf);
    attn_kernel<<<1024, 256, 0, stream>>>(Qbuf, Kbuf, Vbuf, Obuf);
    gemm_out<<<256, 256, 0, stream>>>(Obuf, woutb, out);
}

// Round 12
// 124.110 us; speedup vs baseline: 1.2110x; 1.1001x over previous
//
#include <hip/hip_runtime.h>
#include <hip/hip_bf16.h>

typedef __attribute__((ext_vector_type(8))) short bf16x8;
typedef __attribute__((ext_vector_type(4))) short s16x4;
typedef __attribute__((ext_vector_type(4))) float f32x4;

__device__ __forceinline__ short f2bf(float f) {
    unsigned int u = __builtin_bit_cast(unsigned int, f);
    u += 0x7fffu + ((u >> 16) & 1u);
    return (short)(u >> 16);
}

#define GLDS(g, l) __builtin_amdgcn_global_load_lds( \
    (__attribute__((address_space(1))) void*)(g),    \
    (__attribute__((address_space(3))) void*)(l), 16, 0, 0)

#define BARSB() { __builtin_amdgcn_s_barrier(); __builtin_amdgcn_sched_barrier(0); }
#define VMC8()  { asm volatile("s_waitcnt vmcnt(8)" ::: "memory"); __builtin_amdgcn_sched_barrier(0); }
#define VMC7()  { asm volatile("s_waitcnt vmcnt(7)" ::: "memory"); __builtin_amdgcn_sched_barrier(0); }
#define VMC0()  { asm volatile("s_waitcnt vmcnt(0)" ::: "memory"); __builtin_amdgcn_sched_barrier(0); }

// ---------------- fp32 -> bf16 convert ----------------
__global__ __launch_bounds__(256) void cvt_kernel(const float* __restrict__ in,
                                                  short* __restrict__ out, int n4) {
    int i = blockIdx.x * 256 + threadIdx.x;
    if (i >= n4) return;
    float4 v = reinterpret_cast<const float4*>(in)[i];
    s16x4 r = { f2bf(v.x), f2bf(v.y), f2bf(v.z), f2bf(v.w) };
    reinterpret_cast<s16x4*>(out)[i] = r;
}

#define LDP 72

// ---------------- QKV GEMM (+RoPE), 256x192, loose-wave counted-vmcnt loop -----------
__device__ __forceinline__ void load_a(const short* __restrict__ A, int wr, int lo, int hi,
                                       int mh, bf16x8 aF[4][2]) {
#pragma unroll
    for (int mi = 0; mi < 4; ++mi)
#pragma unroll
        for (int kk = 0; kk < 2; ++kk)
            aF[mi][kk] = *reinterpret_cast<const bf16x8*>(
                &A[(wr * 128 + mh * 64 + mi * 16 + lo) * 64 + (((kk * 4 + hi) ^ (lo & 7)) << 3)]);
}
__device__ __forceinline__ void load_b3(const short* __restrict__ B, int wc, int lo, int hi,
                                        bf16x8 bF[3][2]) {
#pragma unroll
    for (int ni = 0; ni < 3; ++ni)
#pragma unroll
        for (int kk = 0; kk < 2; ++kk)
            bF[ni][kk] = *reinterpret_cast<const bf16x8*>(
                &B[(wc * 48 + ni * 16 + lo) * 64 + (((kk * 4 + hi) ^ (lo & 7)) << 3)]);
}
__device__ __forceinline__ void mfma24(const bf16x8 aF[4][2], const bf16x8 bF[3][2],
                                       f32x4 acc[8][3], int mh) {
#pragma unroll
    for (int mi = 0; mi < 4; ++mi)
#pragma unroll
        for (int ni = 0; ni < 3; ++ni)
#pragma unroll
            for (int kk = 0; kk < 2; ++kk)
                acc[mh * 4 + mi][ni] = __builtin_amdgcn_mfma_f32_16x16x32_bf16(
                    aF[mi][kk], bF[ni][kk], acc[mh * 4 + mi][ni], 0, 0, 0);
}

__global__ __launch_bounds__(512, 1) void gemm_qkv_rope(
    const short* __restrict__ X, const short* __restrict__ W,
    const float* __restrict__ cosT, const float* __restrict__ sinT,
    short* __restrict__ Qo, short* __restrict__ Ko, short* __restrict__ Vo) {
    __shared__ short ldsA[2][16384];   // 2 x 32KB
    __shared__ short ldsB[2][12288];   // 2 x 24KB
    const int tid = threadIdx.x;
    const int lane = tid & 63;
    const int w = tid >> 6;
    const int lo = lane & 15, hi = lane >> 4;
    const int wr = w >> 2, wc = w & 3;   // 2 (M) x 4 (N) waves
    const int lin = blockIdx.x;
    const int xcd = lin & 7;
    const int i_ = lin >> 3;
    const int m0 = ((xcd >> 1) * 4 + (i_ & 3)) * 256;
    const int n0 = ((xcd & 1) * 8 + (i_ >> 2)) * 192;

    f32x4 acc[8][3];
#pragma unroll
    for (int i = 0; i < 8; i++)
#pragma unroll
        for (int j = 0; j < 3; j++) acc[i][j] = {0.f, 0.f, 0.f, 0.f};

    const int srow8 = w * 8 + (lane >> 3);
    const int scx = (((lane & 7) ^ ((lane >> 3) & 7)) << 3);

#define STAGE_A(BUF, KT, IT) GLDS(X + (size_t)(m0 + (IT) * 64 + srow8) * 1024 + ((KT) << 6) + scx, \
                                  (char*)&ldsA[BUF][0] + (IT) * 8192 + w * 1024)
#define STAGE_B(BUF, KT, IT) GLDS(W + (size_t)(n0 + (IT) * 64 + srow8) * 1024 + ((KT) << 6) + scx, \
                                  (char*)&ldsB[BUF][0] + (IT) * 8192 + w * 1024)

    bf16x8 aF[4][2], bF[3][2];

    // prologue: tile 0 -> buf 0 (7 chunks)
    STAGE_B(0, 0, 0); STAGE_B(0, 0, 1); STAGE_B(0, 0, 2);
    STAGE_A(0, 0, 0); STAGE_A(0, 0, 1); STAGE_A(0, 0, 2); STAGE_A(0, 0, 3);

    for (int t = 0; t < 16; ++t) {
        const int c = t & 1;
        if (t < 15) {
            const int nb_ = c ^ 1, t1 = t + 1;
            STAGE_B(nb_, t1, 0); STAGE_B(nb_, t1, 1); STAGE_B(nb_, t1, 2);
            STAGE_A(nb_, t1, 0); STAGE_A(nb_, t1, 1); STAGE_A(nb_, t1, 2); STAGE_A(nb_, t1, 3);
            VMC7();    // waits only the PREVIOUS iter's 7 loads (buf c ready)
        } else {
            VMC0();
        }
        BARSB();       // buf c globally ready
        // compute tile c: no intra-region barriers -> waves drift, LDS/MFMA overlap
        load_a(&ldsA[c][0], wr, lo, hi, 0, aF);
        load_b3(&ldsB[c][0], wc, lo, hi, bF);
        mfma24(aF, bF, acc, 0);
        load_a(&ldsA[c][0], wr, lo, hi, 1, aF);
        mfma24(aF, bF, acc, 1);
        if (t < 15) BARSB();   // all reads of buf c done before next iter stages into it
    }
#undef STAGE_A
#undef STAGE_B

#pragma unroll
    for (int mi = 0; mi < 8; mi++) {
#pragma unroll
        for (int r = 0; r < 4; r++) {
            const int m = m0 + wr * 128 + mi * 16 + (hi << 2) + r;
            const int b_ = m >> 11;
            const int s_ = m & 2047;
#pragma unroll
            for (int ni = 0; ni < 3; ni++) {
                float v = acc[mi][ni][r];
                const int n = n0 + wc * 48 + ni * 16 + lo;
                const int region = n >> 10;
                const int c = n & 1023;
                const int h = c >> 6;
                const int d = c & 63;
                const size_t oidx = ((size_t)(b_ * 16 + h) * 2048 + s_) * 64 + d;
                if (region == 2) {
                    Vo[oidx] = f2bf(v);
                } else {
                    float other = __shfl_xor(v, 1, 64);
                    const int i2 = d >> 1;
                    float cs = cosT[s_ * 32 + i2];
                    float sn = sinT[s_ * 32 + i2];
                    float outv = (d & 1) ? (v * cs + other * sn) : (v * cs - other * sn);
                    if (region == 0) {
                        // fold 1/sqrt(dh) * log2(e) into Q for exp2-domain softmax
                        Qo[oidx] = f2bf(outv * 0.18033688f);
                    } else {
                        Ko[oidx] = f2bf(outv);
                    }
                }
            }
        }
    }
}

// ---------------- Flash attention (exp2 softmax, defer-max, cvt_pk, swizzled K) ------
__device__ __forceinline__ void attn_tile_compute(
    const bf16x8 q0, const bf16x8 q1,
    const short* __restrict__ Ks,          // [64*64] chunk-XOR swizzled
    const short (*Vts)[LDP], short* __restrict__ Pw,
    const int lane, const int w, const bool diag,
    float& m_r, float& l_r, f32x4* __restrict__ o_acc) {
    const int lo = lane & 15, hi = lane >> 4;
    const int sx = lo & 7;

    f32x4 sc[4];
#pragma unroll
    for (int nb = 0; nb < 4; nb++) sc[nb] = {0.f, 0.f, 0.f, 0.f};
#pragma unroll
    for (int nb = 0; nb < 4; nb++) {
        const short* kr = &Ks[(nb * 16 + lo) * 64];
        bf16x8 k0 = *reinterpret_cast<const bf16x8*>(&kr[(hi ^ sx) << 3]);
        sc[nb] = __builtin_amdgcn_mfma_f32_16x16x32_bf16(k0, q0, sc[nb], 0, 0, 0);
        bf16x8 k1 = *reinterpret_cast<const bf16x8*>(&kr[((4 + hi) ^ sx) << 3]);
        sc[nb] = __builtin_amdgcn_mfma_f32_16x16x32_bf16(k1, q1, sc[nb], 0, 0, 0);
    }
    if (diag) {
        const int q_ = w * 16 + lo;
        const int kb = (hi << 2);
#pragma unroll
        for (int nb = 0; nb < 4; nb++) {
            const int k_ = nb * 16 + kb;
#pragma unroll
            for (int r = 0; r < 4; r++)
                if (k_ + r > q_) sc[nb][r] = -1e30f;
        }
    }

    float mx = sc[0][0];
#pragma unroll
    for (int nb = 0; nb < 4; nb++)
#pragma unroll
        for (int r = 0; r < 4; r++) mx = fmaxf(mx, sc[nb][r]);
    mx = fmaxf(mx, __shfl_xor(mx, 16, 64));
    mx = fmaxf(mx, __shfl_xor(mx, 32, 64));

    // defer-max: only rescale when the running max grows by >8 (log2 domain)
    if (!__all(mx <= m_r + 8.0f)) {
        const float mnew = fmaxf(m_r, mx);
        const float alpha = __builtin_amdgcn_exp2f(m_r - mnew);
        m_r = mnew;
        l_r *= alpha;
        float aq[4];
#pragma unroll
        for (int r = 0; r < 4; r++) aq[r] = __shfl(alpha, (hi << 2) + r, 64);
#pragma unroll
        for (int db = 0; db < 4; db++)
#pragma unroll
            for (int r = 0; r < 4; r++) o_acc[db][r] *= aq[r];
    }

    float rs = 0.f;
#pragma unroll
    for (int nb = 0; nb < 4; nb++)
#pragma unroll
        for (int r = 0; r < 4; r++) {
            float e = __builtin_amdgcn_exp2f(sc[nb][r] - m_r);
            sc[nb][r] = e;
            rs += e;
        }
    rs += __shfl_xor(rs, 16, 64);
    rs += __shfl_xor(rs, 32, 64);
    l_r += rs;

    unsigned int* Pw32 = reinterpret_cast<unsigned int*>(Pw);
#pragma unroll
    for (int nb = 0; nb < 4; nb++)
#pragma unroll
        for (int rr = 0; rr < 2; rr++) {
            unsigned int pk;
            asm("v_cvt_pk_bf16_f32 %0, %1, %2"
                : "=v"(pk) : "v"(sc[nb][2 * rr]), "v"(sc[nb][2 * rr + 1]));
            Pw32[lo * (LDP / 2) + nb * 8 + (hi << 1) + rr] = pk;
        }

#pragma unroll
    for (int kk = 0; kk < 2; kk++) {
        bf16x8 pa = *reinterpret_cast<const bf16x8*>(&Pw[lo * LDP + kk * 32 + hi * 8]);
#pragma unroll
        for (int db = 0; db < 4; db++) {
            const int d = db * 16 + lo;
            const int tsw = (kk * 32 + hi * 8) ^ ((((d >> 3) & 7)) << 3);
            bf16x8 vb = *reinterpret_cast<const bf16x8*>(&Vts[d][tsw]);
            o_acc[db] = __builtin_amdgcn_mfma_f32_16x16x32_bf16(pa, vb, o_acc[db], 0, 0, 0);
        }
    }
}

__global__ __launch_bounds__(256) void attn_kernel(
    const short* __restrict__ Q, const short* __restrict__ K,
    const short* __restrict__ V, short* __restrict__ O) {
    __shared__ short Ks[2][64 * 64];    // chunk-XOR swizzled, 16KB
    __shared__ short Vts[2][64][LDP];   // 18KB
    __shared__ short Ps[4][16 * LDP];   // 9KB  -> 43KB total, 3 blocks/CU

    const int tid = threadIdx.x;
    const int lane = tid & 63;
    const int w = tid >> 6;
    const int lo = lane & 15, hi = lane >> 4;
    const int sx = lo & 7;
    const int lin = blockIdx.x;
    const int bh = lin & 31;
    const int qt = 31 - (lin >> 5);     // LPT: heavy blocks first
    const int b_ = bh >> 4, h = bh & 15;
    const size_t base = (size_t)bh * 2048 * 64;

    // staging geometry (K and Q share the pattern)
    const int krow = tid >> 2;              // 0..63
    const int cq = (tid & 3) * 2;           // chunk pair
    const int ksw = krow & 7;

    // Q-hoist: stage Q tile through Ks[0] (swizzled), keep fragments in registers
    bf16x8 q0, q1;
    {
        const short* src = Q + base + (size_t)(qt * 64 + krow) * 64 + cq * 8;
        bf16x8 a = *reinterpret_cast<const bf16x8*>(src);
        bf16x8 b = *reinterpret_cast<const bf16x8*>(src + 8);
        *reinterpret_cast<bf16x8*>(&Ks[0][krow * 64 + ((cq ^ ksw) << 3)]) = a;
        *reinterpret_cast<bf16x8*>(&Ks[0][krow * 64 + (((cq + 1) ^ ksw) << 3)]) = b;
        __syncthreads();
        q0 = *reinterpret_cast<const bf16x8*>(&Ks[0][(w * 16 + lo) * 64 + ((hi ^ sx) << 3)]);
        q1 = *reinterpret_cast<const bf16x8*>(&Ks[0][(w * 16 + lo) * 64 + (((4 + hi) ^ sx) << 3)]);
        __syncthreads();
    }

    float m_r = -1e30f, l_r = 0.f;
    f32x4 o_acc[4];
#pragma unroll
    for (int db = 0; db < 4; db++) o_acc[db] = {0.f, 0.f, 0.f, 0.f};

    // V geometry: thread owns rows (2u, 2u+1), cols vdb8..+7; packed b32 writes
    const int u2 = tid >> 3;                // 0..31
    const int vdb8 = (tid & 7) * 8;
    const int vswz = (tid & 7) << 3;
    const int tw = (2 * u2) ^ vswz;         // even -> b32-aligned

    bf16x8 kr0, kr1, vr0, vr1;
    kr0 = *reinterpret_cast<const bf16x8*>(K + base + (size_t)krow * 64 + cq * 8);
    kr1 = *reinterpret_cast<const bf16x8*>(K + base + (size_t)krow * 64 + cq * 8 + 8);
    vr0 = *reinterpret_cast<const bf16x8*>(V + base + (size_t)(2 * u2) * 64 + vdb8);
    vr1 = *reinterpret_cast<const bf16x8*>(V + base + (size_t)(2 * u2 + 1) * 64 + vdb8);

    int c = 0;
    for (int j = 0; j <= qt; j++) {
        *reinterpret_cast<bf16x8*>(&Ks[c][krow * 64 + ((cq ^ ksw) << 3)]) = kr0;
        *reinterpret_cast<bf16x8*>(&Ks[c][krow * 64 + (((cq + 1) ^ ksw) << 3)]) = kr1;
#pragma unroll
        for (int i = 0; i < 8; i++) {
            unsigned int pv = (unsigned int)(unsigned short)vr0[i] |
                              ((unsigned int)(unsigned short)vr1[i] << 16);
            *reinterpret_cast<unsigned int*>(&Vts[c][vdb8 + i][tw]) = pv;
        }
        __syncthreads();
        if (j < qt) {
            const size_t jb2 = (size_t)(j + 1) * 64;
            kr0 = *reinterpret_cast<const bf16x8*>(K + base + (jb2 + krow) * 64 + cq * 8);
            kr1 = *reinterpret_cast<const bf16x8*>(K + base + (jb2 + krow) * 64 + cq * 8 + 8);
            vr0 = *reinterpret_cast<const bf16x8*>(V + base + (jb2 + 2 * u2) * 64 + vdb8);
            vr1 = *reinterpret_cast<const bf16x8*>(V + base + (jb2 + 2 * u2 + 1) * 64 + vdb8);
        }

        attn_tile_compute(q0, q1, Ks[c], Vts[c], &Ps[w][0], lane, w, j == qt, m_r, l_r, o_acc);
        c ^= 1;
    }

    float inv[4];
#pragma unroll
    for (int r = 0; r < 4; r++) inv[r] = 1.f / __shfl(l_r, (hi << 2) + r, 64);

    short* Op = O + ((size_t)b_ * 2048) * 1024 + (size_t)h * 64;
#pragma unroll
    for (int r = 0; r < 4; r++) {
        const int row = qt * 64 + w * 16 + (hi << 2) + r;
#pragma unroll
        for (int db = 0; db < 4; db++)
            Op[(size_t)row * 1024 + db * 16 + lo] = f2bf(o_acc[db][r] * inv[r]);
    }
}

// ---------------- Out GEMM, 128x128, loose-wave counted-vmcnt loop -------------------
__global__ __launch_bounds__(256) void gemm_out(
    const short* __restrict__ A, const short* __restrict__ W,
    float* __restrict__ C) {
    __shared__ short As[2][128 * 64];
    __shared__ short Bs[2][128 * 64];
    const int tid = threadIdx.x;
    const int lane = tid & 63;
    const int w = tid >> 6;
    const int lo = lane & 15, hi = lane >> 4;
    const int wr = w >> 1, wc = w & 1;
    const int lin = blockIdx.x;
    const int wg = (lin & 7) * 32 + (lin >> 3);
    const int n0 = (wg & 7) * 128;
    const int m0 = (wg >> 3) * 128;
    const int K = 1024;

    f32x4 acc[4][4];
#pragma unroll
    for (int i = 0; i < 4; i++)
#pragma unroll
        for (int j = 0; j < 4; j++) acc[i][j] = {0.f, 0.f, 0.f, 0.f};

    const int srow = w * 8 + (lane >> 3);
    const int sc8 = (lane & 7) * 8;
    const short* gA = A + (size_t)(m0 + srow) * K + sc8;
    const short* gB = W + (size_t)(n0 + srow) * K + sc8;

#pragma unroll
    for (int it = 0; it < 4; it++)
        GLDS(gA + (size_t)it * 32 * K, (char*)As[0] + it * 4096 + w * 1024);
#pragma unroll
    for (int it = 0; it < 4; it++)
        GLDS(gB + (size_t)it * 32 * K, (char*)Bs[0] + it * 4096 + w * 1024);

    for (int t = 0; t < 16; t++) {
        const int c = t & 1;
        if (t < 15) {
            const int k1 = (t + 1) * 64;
#pragma unroll
            for (int it = 0; it < 4; it++)
                GLDS(gA + k1 + (size_t)it * 32 * K, (char*)As[c ^ 1] + it * 4096 + w * 1024);
#pragma unroll
            for (int it = 0; it < 4; it++)
                GLDS(gB + k1 + (size_t)it * 32 * K, (char*)Bs[c ^ 1] + it * 4096 + w * 1024);
            VMC8();
        } else {
            VMC0();
        }
        BARSB();
#pragma unroll
        for (int kk = 0; kk < 2; kk++) {
            bf16x8 a[4], b[4];
#pragma unroll
            for (int mi = 0; mi < 4; mi++)
                a[mi] = *reinterpret_cast<const bf16x8*>(
                    &As[c][(wr * 64 + mi * 16 + lo) * 64 + kk * 32 + hi * 8]);
#pragma unroll
            for (int ni = 0; ni < 4; ni++)
                b[ni] = *reinterpret_cast<const bf16x8*>(
                    &Bs[c][(wc * 64 + ni * 16 + lo) * 64 + kk * 32 + hi * 8]);
#pragma unroll
            for (int mi = 0; mi < 4; mi++)
#pragma unroll
                for (int ni = 0; ni < 4; ni++)
                    acc[mi][ni] = __builtin_amdgcn_mfma_f32_16x16x32_bf16(
                        a[mi], b[ni], acc[mi][ni], 0, 0, 0);
        }
        if (t < 15) BARSB();
    }

#pragma unroll
    for (int mi = 0; mi < 4; mi++) {
#pragma unroll
        for (int r = 0; r < 4; r++) {
            const int m = m0 + wr * 64 + mi * 16 + (hi << 2) + r;
#pragma unroll
            for (int ni = 0; ni < 4; ni++) {
                const int n = n0 + wc * 64 + ni * 16 + lo;
                C[(size_t)m * 1024 + n] = acc[mi][ni][r];
            }
        }
    }
}

extern "C" void kernel_launch(void* const* d_in, const int* in_sizes, int n_in,
                              void* d_out, int out_size, void* d_ws, size_t ws_size,
                              hipStream_t stream) {
    const float* x = (const float*)d_in[0];
    const float* wQKV = (const float*)d_in[1];
    const float* wOut = (const float*)d_in[2];
    const float* cosT = (const float*)d_in[3];
    const float* sinT = (const float*)d_in[4];
    float* out = (float*)d_out;

    char* ws = (char*)d_ws;
    const size_t MB = 1024 * 1024;
    short* xb    = (short*)(ws);             // 8MB
    short* wqkvb = (short*)(ws + 8 * MB);    // 6MB
    short* woutb = (short*)(ws + 14 * MB);   // 2MB
    short* Qbuf  = (short*)(ws + 16 * MB);   // 8MB
    short* Kbuf  = (short*)(ws + 24 * MB);   // 8MB
    short* Vbuf  = (short*)(ws + 32 * MB);   // 8MB
    short* Obuf  = (short*)(ws + 40 * MB);   // 8MB (attn out, bf16)

    cvt_kernel<<<4096, 256, 0, stream>>>(x, xb, 1048576);
    cvt_kernel<<<3072, 256, 0, stream>>>(wQKV, wqkvb, 786432);
    cvt_kernel<<<1024, 256, 0, stream>>>(wOut, woutb, 262144);

    gemm_qkv_rope<<<256, 512, 0, stream>>>(xb, wqkvb, cosT, sinT, Qbuf, Kbuf, Vbuf);
    attn_kernel<<<1024, 256, 0, stream>>>(Qbuf, Kbuf, Vbuf, Obuf);
    gemm_out<<<256, 256, 0, stream>>>(Obuf, woutb, out);
}